// Round 12
// baseline (1029.960 us; speedup 1.0000x reference)
//
#include <hip/hip_runtime.h>
#include <stdint.h>
#include <math.h>

// RNN predictor: B=2048, T=1024 teacher + FUT=64 AR, H=128.
// Round-12: R11 step (fp16 hi/lo weights, single-fp16 h, pi-permuted LDS
// layout, one barrier/step) with 2x the independent recurrence chains:
//  - SPB=2, grid=1024, __launch_bounds__(256,4) -> 4 blocks/CU, 4 waves/SIMD.
//    R11 was latency-bound on the serial chain (barrier->ds_read->MFMA->
//    tanh->ds_write->barrier) with only 2 chains/SIMD; VGPR=72 leaves room
//    for 4. MFMA pipe has 3x headroom for the doubled M-waste.
//  - h-writes exec-masked to g<SPB (2-way banks, free); garbage lanes g>=2
//    never reach outbuf/AR (flush+feedback indices < SPB only).

#define TLEN  1024
#define FUT   64
#define HID   128
#define SPB   2
#define NT    256
#define NSTEP (TLEN + FUT)

typedef float f32x4 __attribute__((ext_vector_type(4)));
typedef _Float16 f16x8 __attribute__((ext_vector_type(8)));
typedef uint32_t u32x4 __attribute__((ext_vector_type(4)));

__device__ __forceinline__ f16x8 asf16(u32x4 v) {
    return __builtin_bit_cast(f16x8, v);
}
__device__ __forceinline__ float fast_tanh(float v) {
    return 1.0f - 2.0f / (__expf(2.0f * v) + 1.0f);   // saturates correctly
}

__global__ __launch_bounds__(NT, 4) void rnn_kernel(
    const float* __restrict__ x,      // [B, T]
    const float* __restrict__ W_ih,   // [H, 1]
    const float* __restrict__ W_hh,   // [H, H]
    const float* __restrict__ b_ih,   // [H]
    const float* __restrict__ b_hh,   // [H]
    const float* __restrict__ W_out,  // [1, H]
    const float* __restrict__ b_out,  // [1]
    float* __restrict__ out)          // [B, T+FUT]
{
    // h: [p][row s][u32 m] ; u32 m holds fp16 cols (32(m&3)+(m>>2), +16);
    // byte ^= (row<<5). Same layout as R11 (verified).
    __shared__ __align__(16) unsigned short lds_h[2][SPB * HID];
    __shared__ __align__(16) float xstg[128][4];        // [t][sample]
    __shared__ __align__(16) float outbuf[2][SPB][68];  // o ring, padded
    __shared__ __align__(16) float opart[2][16];        // [sample*4 + wave]

    const int tid  = threadIdx.x;
    const int lane = tid & 63;
    const int wid  = tid >> 6;        // wave w: cols 32w..32w+31
    const int l15  = lane & 15;
    const int g    = lane >> 4;       // lane-group = sample index in epilogue
    const int s0   = blockIdx.x * SPB;

    // ---- weight B-fragments (fp16 hi/lo), 64 VGPRs ----
    // B slot (kt, g, e) -> k = 16e + 4kt + g (pi permutation, R11-verified).
    const int j0 = wid * 32 + l15;
    const int j1 = j0 + 16;
    f16x8 WhiA[4], WloA[4], WhiB[4], WloB[4];
    {
        const float* r0 = W_hh + (size_t)j0 * HID;
        const float* r1 = W_hh + (size_t)j1 * HID;
        #pragma unroll
        for (int kt = 0; kt < 4; ++kt) {
            #pragma unroll
            for (int e = 0; e < 8; ++e) {
                const int k = 16 * e + 4 * kt + g;
                const float wa = r0[k];
                const _Float16 wha = (_Float16)wa;
                WhiA[kt][e] = wha;
                WloA[kt][e] = (_Float16)((wa - (float)wha) * 4096.0f);
                const float wb = r1[k];
                const _Float16 whb = (_Float16)wb;
                WhiB[kt][e] = whb;
                WloB[kt][e] = (_Float16)((wb - (float)whb) * 4096.0f);
            }
        }
    }
    const float bias0 = b_ih[j0] + b_hh[j0];
    const float bias1 = b_ih[j1] + b_hh[j1];
    const float wih0  = W_ih[j0], wih1 = W_ih[j1];
    const float wout0 = W_out[j0], wout1 = W_out[j1];
    const float bo    = b_out[0];
    const float CLO   = 1.0f / 4096.0f;   // exact pow2 rescale of the lo product

    // ---- LDS byte offsets ----
    // A-read: lanes with (l15&3)==0 and s_=l15>>2 < SPB; 16B per kt.
    const int s_ = l15 >> 2;
    int aoff[4];
    #pragma unroll
    for (int kt = 0; kt < 4; ++kt)
        aoff[kt] = s_ * 256 + (((4 * kt + g) * 16) ^ (s_ << 5));
    // h-write: lanes g<SPB; sample g, packed (j0,j1) fp16 pair -> one b32.
    const int woff = g * 256 + ((l15 * 16 + wid * 4) ^ (g << 5));

    for (int idx = tid; idx < SPB * HID; idx += NT)
        ((uint32_t*)lds_h)[idx] = 0;
    if (tid < 32) ((float*)opart)[tid] = 0.0f;
    __syncthreads();

    // A-frags zeroed once; exec-masked loads keep inactive lanes at zero.
    u32x4 A_[4];
    #pragma unroll
    for (int kt = 0; kt < 4; ++kt) A_[kt] = (u32x4){0, 0, 0, 0};

    for (int i = 0; i < NSTEP; ++i) {
        const int p = i & 1;

        // refill x chunk every 128 teacher steps (coalesced along t)
        if (i < TLEN && (i & 127) == 0) {
            const int t = tid & 127, s = tid >> 7;   // 256 threads = 128 t x 2 s
            xstg[t][s] = x[(size_t)(s0 + s) * TLEN + (i + t)];
            __syncthreads();
        }

        // flush a full 64-entry output ring (o_{i-65}..o_{i-2})
        if (i > 64 && (i & 63) == 1 && tid < 16 * SPB) {
            const int q = ((i - 65) >> 6) & 1;
            const int s = tid >> 4, c4 = (tid & 15) * 4;
            const f32x4 v = *(const f32x4*)&outbuf[q][s][c4];
            *(f32x4*)&out[(size_t)(s0 + s) * NSTEP + (i - 65) + c4] = v;
        }

        // A-fragments of h(t): rows 0..SPB-1 only; other lanes stay zero
        const char* hb = (const char*)lds_h[p];
        if ((l15 & 3) == 0 && l15 < 4 * SPB) {
            #pragma unroll
            for (int kt = 0; kt < 4; ++kt)
                A_[kt] = *(const u32x4*)(hb + aoff[kt]);
        }

        // finish o_{i-1}: lane l15 reads slot l15 = sample(l15>>2), wave(l15&3)
        float ov = opart[p ^ 1][l15];
        ov += __shfl_xor(ov, 1);
        ov += __shfl_xor(ov, 2);
        const float o = ov + bo;        // lane 4s holds o(sample s); junk at i==0
        if (i > 0 && wid == 0 && g == 0 && (l15 & 3) == 0 && l15 < 4 * SPB)
            outbuf[((i - 1) >> 6) & 1][l15 >> 2][(i - 1) & 63] = o;

        // 16 MFMA in 4 independent chains (full K=32 each)
        f32x4 pha = {0.f,0.f,0.f,0.f}, phb = pha, pla = pha, plb = pha;
        #pragma unroll
        for (int kt = 0; kt < 4; ++kt) {
            pha = __builtin_amdgcn_mfma_f32_16x16x32_f16(asf16(A_[kt]), WhiA[kt], pha, 0, 0, 0);
            phb = __builtin_amdgcn_mfma_f32_16x16x32_f16(asf16(A_[kt]), WhiB[kt], phb, 0, 0, 0);
            pla = __builtin_amdgcn_mfma_f32_16x16x32_f16(asf16(A_[kt]), WloA[kt], pla, 0, 0, 0);
            plb = __builtin_amdgcn_mfma_f32_16x16x32_f16(asf16(A_[kt]), WloB[kt], plb, 0, 0, 0);
        }

        // per-lane input for sample g (uniform branch; g>=SPB lanes harmless)
        float in;
        if (i < TLEN) in = xstg[i & 127][g & (SPB - 1)];
        else          in = __shfl(o, (g & (SPB - 1)) << 2);

        // epilogue: ONE row per lane (sample g, cols j0/j1)
        const float S0 = fmaf(CLO, pla[0], pha[0]) + bias0 + in * wih0;
        const float S1 = fmaf(CLO, plb[0], phb[0]) + bias1 + in * wih1;
        const float h0 = fast_tanh(S0);
        const float h1 = fast_tanh(S1);

        // pack (fp16(h0), fp16(h1)) -> one b32 write, lanes g<SPB only
        const _Float16 q0 = (_Float16)h0;          // RNE
        const _Float16 q1 = (_Float16)h1;
        const uint32_t pv = (uint32_t)__builtin_bit_cast(unsigned short, q0)
                          | ((uint32_t)__builtin_bit_cast(unsigned short, q1) << 16);
        if (g < SPB)
            *(uint32_t*)((char*)lds_h[p ^ 1] + woff) = pv;

        // o-partials: reduce this wave's 32 cols for sample g
        float op = h0 * wout0 + h1 * wout1;
        op += __shfl_xor(op, 1);
        op += __shfl_xor(op, 2);
        op += __shfl_xor(op, 4);
        op += __shfl_xor(op, 8);
        if (l15 == 0) opart[p][g * 4 + wid] = op;

        __syncthreads();   // the one per-step barrier
    }

    // tail: finish o_{NSTEP-1}, flush last 64 outputs
    {
        float ov = opart[(NSTEP - 1) & 1][l15];
        ov += __shfl_xor(ov, 1);
        ov += __shfl_xor(ov, 2);
        const float o = ov + bo;
        if (wid == 0 && g == 0 && (l15 & 3) == 0 && l15 < 4 * SPB)
            outbuf[((NSTEP - 1) >> 6) & 1][l15 >> 2][(NSTEP - 1) & 63] = o;
    }
    __syncthreads();
    if (tid < 16 * SPB) {   // flush t = 1024..1087 (ring q = 0)
        const int s = tid >> 4, c4 = (tid & 15) * 4;
        const f32x4 v = *(const f32x4*)&outbuf[0][s][c4];
        *(f32x4*)&out[(size_t)(s0 + s) * NSTEP + TLEN + c4] = v;
    }
}

extern "C" void kernel_launch(void* const* d_in, const int* in_sizes, int n_in,
                              void* d_out, int out_size, void* d_ws, size_t ws_size,
                              hipStream_t stream) {
    const float* x     = (const float*)d_in[0];
    const float* W_ih  = (const float*)d_in[1];
    const float* W_hh  = (const float*)d_in[2];
    const float* b_ih  = (const float*)d_in[3];
    const float* b_hh  = (const float*)d_in[4];
    const float* W_out = (const float*)d_in[5];
    const float* b_out = (const float*)d_in[6];
    float* out = (float*)d_out;

    dim3 grid(2048 / SPB);   // 1024 blocks -> 4 per CU
    dim3 block(NT);
    rnn_kernel<<<grid, block, 0, stream>>>(x, W_ih, W_hh, b_ih, b_hh,
                                           W_out, b_out, out);
}

// Round 13
// 801.217 us; speedup vs baseline: 1.2855x; 1.2855x over previous
//
#include <hip/hip_runtime.h>
#include <stdint.h>
#include <math.h>

// RNN predictor: B=2048, T=1024 teacher + FUT=64 AR, H=128.
// Round-13: TRANSPOSED MFMA. Compute S^T = W.h^T:
//   A = W fragments (M = 16 j-rows, fully used), B = h (N = 16 sample cols).
//   k-permutation pi(k) = ((k&3)*4 + ((k>>2)&3))*8 + (k>>4) applied to BOTH
//   A (at init) and B (LDS layout) -> contraction invariant.
//   Per wave: 2 j-tiles (j = 32*wid + 16q + ...) x 4 kt x {Whi, Wlo} =
//   16 MFMA/wave-step for 8 samples (2 MFMA/sample — zero M/N waste modulo
//   the 8/16 sample fill).
// C layout: lane (g,l15) holds S[j = 32wid+16q+4g+r][sample l15] -> epilogue
// is 8 tanh/lane (all lanes useful), h' packs (q0,q1) into 4 ds_write_b32 at
// pi-addresses, o = Wout.h via 8 fma + xor16/32 + 1 opart b32; next step's
// o-finish is one f32x4 read + 3 adds — every lane then holds o for its own
// sample, so AR feedback needs no shuffles at all.
// fp16 numerics as R11 (verified): W = Whi + Wlo*2^-12 (Wlo stored x4096),
// h single fp16 RNE. One barrier/step. grid=256, 1 block/CU, 4 waves.

#define TLEN  1024
#define FUT   64
#define HID   128
#define SPB   8
#define NT    256
#define NSTEP (TLEN + FUT)

typedef float f32x4 __attribute__((ext_vector_type(4)));
typedef _Float16 f16x8 __attribute__((ext_vector_type(8)));
typedef uint32_t u32x4 __attribute__((ext_vector_type(4)));

__device__ __forceinline__ f16x8 asf16(u32x4 v) {
    return __builtin_bit_cast(f16x8, v);
}
__device__ __forceinline__ float fast_tanh(float v) {
    return 1.0f - 2.0f / (__expf(2.0f * v) + 1.0f);   // saturates correctly
}

__global__ __launch_bounds__(NT, 1) void rnn_kernel(
    const float* __restrict__ x,      // [B, T]
    const float* __restrict__ W_ih,   // [H, 1]
    const float* __restrict__ W_hh,   // [H, H]
    const float* __restrict__ b_ih,   // [H]
    const float* __restrict__ b_hh,   // [H]
    const float* __restrict__ W_out,  // [1, H]
    const float* __restrict__ b_out,  // [1]
    float* __restrict__ out)          // [B, T+FUT]
{
    // h: [p][row s=0..15][pi(k)] fp16 (rows 8-15 garbage-but-finite lanes),
    // byte ^= (s&7)<<4. 16 rows x 256B x 2 bufs = 8KB.
    __shared__ __align__(16) unsigned short lds_h[2][16 * HID];
    __shared__ __align__(16) float xstg[128][SPB];      // [t][sample]
    __shared__ __align__(16) float outbuf[2][SPB][68];  // o ring, padded
    __shared__ __align__(16) float opart[2][16][4];     // [sample][wave]

    const int tid  = threadIdx.x;
    const int lane = tid & 63;
    const int wid  = tid >> 6;        // wave w: j-rows 32w..32w+31
    const int l15  = lane & 15;       // = SAMPLE index (C col / B col / h row)
    const int g    = lane >> 4;
    const int s0   = blockIdx.x * SPB;

    // ---- A-fragments: W rows, pi-permuted k. 64 VGPRs (fp16 hi/lo). ----
    // A slot (tile kt, g, e) -> k = kt + 4g + 16e. A row m = l15.
    f16x8 Whi[2][4], Wlo[2][4];
    #pragma unroll
    for (int q = 0; q < 2; ++q) {
        const float* row = W_hh + (size_t)(32 * wid + 16 * q + l15) * HID;
        #pragma unroll
        for (int kt = 0; kt < 4; ++kt) {
            #pragma unroll
            for (int e = 0; e < 8; ++e) {
                const float w = row[kt + 4 * g + 16 * e];
                const _Float16 wh = (_Float16)w;
                Whi[q][kt][e] = wh;
                Wlo[q][kt][e] = (_Float16)((w - (float)wh) * 4096.0f);
            }
        }
    }
    // ---- per-lane C-row constants: j = 32wid + 16q + 4g + r ----
    float bias[2][4], wih[2][4], wout[2][4];
    #pragma unroll
    for (int q = 0; q < 2; ++q)
        #pragma unroll
        for (int r = 0; r < 4; ++r) {
            const int j = 32 * wid + 16 * q + 4 * g + r;
            bias[q][r] = b_ih[j] + b_hh[j];
            wih[q][r]  = W_ih[j];
            wout[q][r] = W_out[j];
        }
    const float bo  = b_out[0];
    const float CLO = 1.0f / 4096.0f;

    // ---- LDS byte offsets (row = l15 both sides; swizzle ^ (l15&7)<<4) ----
    const int swz = (l15 & 7) << 4;
    int boff[4];   // B-read: tile kt, 16B at pi-slot (kt*4+g)*8
    #pragma unroll
    for (int kt = 0; kt < 4; ++kt)
        boff[kt] = l15 * 256 + (((kt * 4 + g) * 16) ^ swz);
    int woff[4];   // h-write: k = 32wid+16q+4g+r -> pi = (r*4+g)*8 + 2wid + q
    #pragma unroll
    for (int r = 0; r < 4; ++r)
        woff[r] = l15 * 256 + ((((r * 4 + g) * 8 + 2 * wid) * 2) ^ swz);

    for (int idx = tid; idx < 16 * HID; idx += NT)
        ((uint32_t*)lds_h)[idx] = 0;                    // both h buffers
    for (int idx = tid; idx < 2 * 16 * 4; idx += NT)
        ((float*)opart)[idx] = 0.0f;
    __syncthreads();

    for (int i = 0; i < NSTEP; ++i) {
        const int p = i & 1;

        // refill x chunk every 128 teacher steps (coalesced along t)
        if (i < TLEN && (i & 127) == 0) {
            #pragma unroll
            for (int pass = 0; pass < 4; ++pass) {
                const int idx = pass * NT + tid;
                const int t = idx & 127, s = idx >> 7;
                xstg[t][s] = x[(size_t)(s0 + s) * TLEN + (i + t)];
            }
            __syncthreads();
        }

        // flush a full 64-entry output ring (o_{i-65}..o_{i-2})
        if (i > 64 && (i & 63) == 1 && tid < 16 * SPB) {
            const int q = ((i - 65) >> 6) & 1;
            const int s = tid >> 4, c4 = (tid & 15) * 4;
            const f32x4 v = *(const f32x4*)&outbuf[q][s][c4];
            *(f32x4*)&out[(size_t)(s0 + s) * NSTEP + (i - 65) + c4] = v;
        }

        // B-fragments: h(t) for sample l15 (all 64 lanes; rows 8-15 junk-safe)
        const char* hb = (const char*)lds_h[p];
        u32x4 B_[4];
        #pragma unroll
        for (int kt = 0; kt < 4; ++kt)
            B_[kt] = *(const u32x4*)(hb + boff[kt]);

        // finish o_{i-1}: one f32x4 read + 3 adds; EVERY lane gets its sample's o
        const f32x4 opv = *(const f32x4*)&opart[p ^ 1][l15][0];
        const float o = opv[0] + opv[1] + opv[2] + opv[3] + bo;
        if (i > 0 && wid == 0 && g == 0 && l15 < SPB)
            outbuf[((i - 1) >> 6) & 1][l15][(i - 1) & 63] = o;

        // 16 MFMA in 4 independent chains: acc[q][hi/lo]
        f32x4 aH0 = {0.f,0.f,0.f,0.f}, aL0 = aH0, aH1 = aH0, aL1 = aH0;
        #pragma unroll
        for (int kt = 0; kt < 4; ++kt) {
            aH0 = __builtin_amdgcn_mfma_f32_16x16x32_f16(Whi[0][kt], asf16(B_[kt]), aH0, 0, 0, 0);
            aH1 = __builtin_amdgcn_mfma_f32_16x16x32_f16(Whi[1][kt], asf16(B_[kt]), aH1, 0, 0, 0);
            aL0 = __builtin_amdgcn_mfma_f32_16x16x32_f16(Wlo[0][kt], asf16(B_[kt]), aL0, 0, 0, 0);
            aL1 = __builtin_amdgcn_mfma_f32_16x16x32_f16(Wlo[1][kt], asf16(B_[kt]), aL1, 0, 0, 0);
        }

        // input for this lane's sample (uniform branch; l15>=8 lanes junk-safe)
        float in;
        if (i < TLEN) in = xstg[i & 127][l15 & (SPB - 1)];
        else          in = o;                       // AR: no shuffle needed

        // epilogue: 8 S-values per lane (q,r); tanh; pack (q0,q1) -> 4 b32
        char* hw = (char*)lds_h[p ^ 1];
        float op = 0.0f;
        #pragma unroll
        for (int r = 0; r < 4; ++r) {
            const float S0 = fmaf(CLO, aL0[r], aH0[r]) + bias[0][r] + in * wih[0][r];
            const float S1 = fmaf(CLO, aL1[r], aH1[r]) + bias[1][r] + in * wih[1][r];
            const float h0 = fast_tanh(S0);         // q=0
            const float h1 = fast_tanh(S1);         // q=1
            op = fmaf(h0, wout[0][r], op);
            op = fmaf(h1, wout[1][r], op);
            const _Float16 q0 = (_Float16)h0;
            const _Float16 q1 = (_Float16)h1;
            const uint32_t pv = (uint32_t)__builtin_bit_cast(unsigned short, q0)
                              | ((uint32_t)__builtin_bit_cast(unsigned short, q1) << 16);
            *(uint32_t*)(hw + woff[r]) = pv;
        }

        // o-partials: sum over g (xor16/32), store per (sample, wave)
        op += __shfl_xor(op, 16);
        op += __shfl_xor(op, 32);
        if (g == 0) opart[p][l15][wid] = op;

        __syncthreads();   // the one per-step barrier
    }

    // tail: finish o_{NSTEP-1}, flush last 64 outputs
    {
        const f32x4 opv = *(const f32x4*)&opart[(NSTEP - 1) & 1][l15][0];
        const float o = opv[0] + opv[1] + opv[2] + opv[3] + bo;
        if (wid == 0 && g == 0 && l15 < SPB)
            outbuf[((NSTEP - 1) >> 6) & 1][l15][(NSTEP - 1) & 63] = o;
    }
    __syncthreads();
    if (tid < 16 * SPB) {   // flush t = 1024..1087 (ring q = 0)
        const int s = tid >> 4, c4 = (tid & 15) * 4;
        const f32x4 v = *(const f32x4*)&outbuf[0][s][c4];
        *(f32x4*)&out[(size_t)(s0 + s) * NSTEP + TLEN + c4] = v;
    }
}

extern "C" void kernel_launch(void* const* d_in, const int* in_sizes, int n_in,
                              void* d_out, int out_size, void* d_ws, size_t ws_size,
                              hipStream_t stream) {
    const float* x     = (const float*)d_in[0];
    const float* W_ih  = (const float*)d_in[1];
    const float* W_hh  = (const float*)d_in[2];
    const float* b_ih  = (const float*)d_in[3];
    const float* b_hh  = (const float*)d_in[4];
    const float* W_out = (const float*)d_in[5];
    const float* b_out = (const float*)d_in[6];
    float* out = (float*)d_out;

    dim3 grid(2048 / SPB);   // 256 blocks -> 1 per CU, full chip
    dim3 block(NT);
    rnn_kernel<<<grid, block, 0, stream>>>(x, W_ih, W_hh, b_ih, b_hh,
                                           W_out, b_out, out);
}